// Round 5
// baseline (1353.095 us; speedup 1.0000x reference)
//
#include <hip/hip_runtime.h>

#define NTOK 8192
#define DIN  1024
#define DH   4096
#define DOUT 1024
#define NE   8
#define MAXT 72                   // ceil(16384/256) + 8 experts of padding
#define SLOTCAP (MAXT*256)        // 18432

typedef __bf16 bf16x8 __attribute__((ext_vector_type(8)));
typedef float  f32x4  __attribute__((ext_vector_type(4)));

// ---- workspace layout (bytes) ----
// WT is shared: holds W1^T during gemm1, then is overwritten with W2^T
// (transpose launched between the two GEMMs, stream-ordered).
constexpr size_t OFF_WT   = 0;            // 8*1024*4096*2 = 67108864
constexpr size_t OFF_XB   = 67108864;     // 8192*1024*2   = 16777216
constexpr size_t OFF_H    = 83886080;     // 18432*4096*2  = 150994944
constexpr size_t OFF_SROW = 234881024;    // 18432*4
constexpr size_t OFF_SW   = 234954752;    // 18432*4
constexpr size_t OFF_TIDX = 235028480;    // 8192*2*4
constexpr size_t OFF_TW   = 235094016;    // 8192*2*4
constexpr size_t OFF_CTRL = 235159552;    // count[8]@0, fill[8]@32, tile_off[9]@64
constexpr size_t OFF_PART = 235159680;    // 2048*8*4
// total = 235225216 bytes

__device__ __forceinline__ ushort f2bf(float f){
  unsigned u = __float_as_uint(f);
  u += 0x7fff + ((u >> 16) & 1);          // RNE
  return (ushort)(u >> 16);
}

#define GLDS(g,l) __builtin_amdgcn_global_load_lds( \
    (const __attribute__((address_space(1))) void*)(g), \
    (__attribute__((address_space(3))) void*)(l), 16, 0, 0)

#define SBAR __builtin_amdgcn_sched_barrier(0)
#define WBAR __builtin_amdgcn_s_barrier()
#define VMCNT(n) asm volatile("s_waitcnt vmcnt(" #n ")" ::: "memory")

// ---------------- x -> bf16 ----------------
__global__ void k_cvt_x(const float4* __restrict__ x, ushort4* __restrict__ xb){
  int i = blockIdx.x * 256 + threadIdx.x;
  float4 v = x[i];
  ushort4 o;
  o.x = f2bf(v.x); o.y = f2bf(v.y); o.z = f2bf(v.z); o.w = f2bf(v.w);
  xb[i] = o;
}

// ------------- W[E][R][C] f32 -> WT[E][C][R] bf16 -------------
__global__ void k_transpose(const float* __restrict__ W, ushort* __restrict__ WT, int R, int C){
  __shared__ ushort tl[64][65];
  int e  = blockIdx.z;
  int r0 = blockIdx.x * 64, c0 = blockIdx.y * 64;
  const float* Wp  = W  + (size_t)e * R * C;
  ushort*      WTp = WT + (size_t)e * R * C;
  int tr = threadIdx.x >> 6, tc = threadIdx.x & 63;
#pragma unroll
  for (int i = 0; i < 16; i++){
    int r = tr + i * 4;
    tl[r][tc] = f2bf(Wp[(size_t)(r0 + r) * C + c0 + tc]);
  }
  __syncthreads();
#pragma unroll
  for (int i = 0; i < 16; i++){
    int r = tr + i * 4;
    WTp[(size_t)(c0 + r) * R + r0 + tc] = tl[tc][r];
  }
}

// ---------------- gate: logits, softmax, top-2, counts ----------------
__global__ void k_gate(const float* __restrict__ x, const float* __restrict__ gw,
                       const float* __restrict__ gb, float* __restrict__ probs_out,
                       int* __restrict__ topk_idx, float* __restrict__ topk_w,
                       int* __restrict__ count, float* __restrict__ partial){
  __shared__ float psum[8];
  __shared__ int   pcnt[8];
  int wv = threadIdx.x >> 6, lane = threadIdx.x & 63;
  int row = blockIdx.x * 4 + wv;
  if (threadIdx.x < 8){ psum[threadIdx.x] = 0.f; pcnt[threadIdx.x] = 0; }
  __syncthreads();

  const float4* x4 = (const float4*)(x + (size_t)row * DIN);
  float acc[8];
#pragma unroll
  for (int e = 0; e < 8; e++) acc[e] = 0.f;
#pragma unroll
  for (int j = 0; j < 4; j++){
    float4 v = x4[j * 64 + lane];
    int kbase = (j * 64 + lane) * 4;
#pragma unroll
    for (int c = 0; c < 4; c++){
      float xv = (&v.x)[c];
      const float4* g4 = (const float4*)(gw + (size_t)(kbase + c) * 8);
      float4 g0 = g4[0], g1 = g4[1];
      acc[0] += xv * g0.x; acc[1] += xv * g0.y; acc[2] += xv * g0.z; acc[3] += xv * g0.w;
      acc[4] += xv * g1.x; acc[5] += xv * g1.y; acc[6] += xv * g1.z; acc[7] += xv * g1.w;
    }
  }
#pragma unroll
  for (int e = 0; e < 8; e++)
#pragma unroll
    for (int off = 32; off; off >>= 1) acc[e] += __shfl_xor(acc[e], off, 64);

  float lg[8], p[8], mx = -1e30f, s = 0.f;
#pragma unroll
  for (int e = 0; e < 8; e++){ lg[e] = acc[e] + gb[e]; mx = fmaxf(mx, lg[e]); }
#pragma unroll
  for (int e = 0; e < 8; e++){ p[e] = expf(lg[e] - mx); s += p[e]; }
  float inv = 1.f / s;
#pragma unroll
  for (int e = 0; e < 8; e++) p[e] *= inv;

  if (lane < 8) probs_out[(size_t)row * 8 + lane] = p[lane];

  if (lane == 0){
    int i1 = 0; float v1 = p[0];
#pragma unroll
    for (int e = 1; e < 8; e++) if (p[e] > v1){ v1 = p[e]; i1 = e; }
    int i2 = -1; float v2 = -1.f;
#pragma unroll
    for (int e = 0; e < 8; e++){ if (e == i1) continue; if (p[e] > v2){ v2 = p[e]; i2 = e; } }
    float denom = 1.f / (v1 + v2 + 1e-10f);
    topk_idx[row * 2]     = i1;  topk_idx[row * 2 + 1] = i2;
    topk_w  [row * 2]     = v1 * denom;  topk_w[row * 2 + 1] = v2 * denom;
    atomicAdd(&pcnt[i1], 1); atomicAdd(&pcnt[i2], 1);
  }
  if (lane < 8) atomicAdd(&psum[lane], p[lane]);
  __syncthreads();
  if (threadIdx.x < 8){
    partial[(size_t)blockIdx.x * 8 + threadIdx.x] = psum[threadIdx.x];
    if (pcnt[threadIdx.x]) atomicAdd(&count[threadIdx.x], pcnt[threadIdx.x]);
  }
}

// ---------------- aux loss + tile offsets (256-granular tiles) ----------------
__global__ void k_aux(const float* __restrict__ partial, const int* __restrict__ count,
                      float* __restrict__ aux_out, int* __restrict__ tile_off){
  __shared__ float red[256];
  __shared__ float tot[8];
  int t = threadIdx.x, e = t & 7;
  float s = 0.f;
  for (int b = (t >> 3); b < 2048; b += 32) s += partial[(size_t)b * 8 + e];
  red[t] = s; __syncthreads();
  if (t < 8){ float v = 0.f; for (int c = 0; c < 32; c++) v += red[c * 8 + t]; tot[t] = v; }
  __syncthreads();
  if (t == 0){
    float aux = 0.f;
    for (int i = 0; i < 8; i++){
      float m = tot[i] * (1.f / 8192.f);
      aux += m * logf(m * 8.f + 1e-10f);
    }
    aux_out[0] = aux;
    int off = 0;
    for (int i = 0; i < 8; i++){ tile_off[i] = off; off += (count[i] + 255) >> 8; }
    tile_off[8] = off;
  }
}

// ---------------- scatter assignments into padded slots ----------------
__global__ void k_scatter(const int* __restrict__ topk_idx, const float* __restrict__ topk_w,
                          const int* __restrict__ tile_off, int* __restrict__ fill,
                          int* __restrict__ slot_row, float* __restrict__ slot_w){
  int i = blockIdx.x * 256 + threadIdx.x;
  int row = i >> 1;
  int e = topk_idx[i];
  float w = topk_w[i];
  int lane = threadIdx.x & 63;
  int pos = 0;
#pragma unroll
  for (int ex = 0; ex < 8; ex++){
    unsigned long long mask = __ballot(e == ex);
    if (e == ex){
      int leader = __ffsll((long long)mask) - 1;
      int base = 0;
      if (lane == leader) base = atomicAdd(&fill[ex], (int)__popcll(mask));
      base = __shfl(base, leader, 64);
      pos = base + (int)__popcll(mask & ((1ull << lane) - 1ull));
    }
  }
  int slot = tile_off[e] * 256 + pos;
  slot_row[slot] = row;
  slot_w[slot]   = w;
}

// =====================================================================
// 256x(BN) 8-wave, BK=64, double-buffered, phase-split GEMM with
// counted vmcnt (T3+T4), LDS XOR-swizzle via pre-swizzled global source
// (T2, rule 21), setprio around MFMA clusters (T5), bijective XCD
// swizzle (T1). MODE 0: A = gathered XB rows, epilogue relu+bias -> H.
// MODE 1: A = H rows (slot-linear), epilogue weighted atomicAdd -> out.
// =====================================================================
#define READ_A(dst, mh, kk) do {                                          \
  _Pragma("unroll")                                                       \
  for (int i_ = 0; i_ < 4; i_++)                                          \
    dst[i_] = *(const bf16x8*)(Ab + aRowBase + ((mh)*4 + i_)*1024 + (foff ^ ((kk)*32))); \
} while(0)

#define READ_Bf(dst, kk) do {                                             \
  _Pragma("unroll")                                                       \
  for (int nj_ = 0; nj_ < NREP; nj_++)                                    \
    dst[nj_] = *(const bf16x8*)(Bb + bRowBase + nj_*1024 + (foff ^ ((kk)*32))); \
} while(0)

#define MFMA_CL(aset, bset, mh) do {                                      \
  __builtin_amdgcn_s_setprio(1);                                          \
  _Pragma("unroll")                                                       \
  for (int i_ = 0; i_ < 4; i_++)                                          \
    _Pragma("unroll")                                                     \
    for (int nj_ = 0; nj_ < NREP; nj_++)                                  \
      acc[(mh)*4 + i_][nj_] = __builtin_amdgcn_mfma_f32_16x16x32_bf16(    \
          aset[i_], bset[nj_], acc[(mh)*4 + i_][nj_], 0, 0, 0);           \
  __builtin_amdgcn_s_setprio(0);                                          \
} while(0)

template<int KDIM, int NTOTAL, int NREP, int MODE>
__global__ __launch_bounds__(512, 2) void k_gemm8(
    const ushort* __restrict__ Ag, const ushort* __restrict__ Wt,
    const float* __restrict__ bias, const int* __restrict__ slot_row,
    const float* __restrict__ slot_w, const int* __restrict__ tile_off,
    ushort* __restrict__ Hout, float* __restrict__ out)
{
  constexpr int BN = NREP * 64;          // 256 (gemm1) / 128 (gemm2)
  constexpr int NTN = NTOTAL / BN;
  constexpr int NT = KDIM / 64;          // K-tiles
  constexpr int BQ = NREP;               // B staging chunks / thread

  __shared__ __align__(16) ushort As[2][256 * 64];
  __shared__ __align__(16) ushort Bs[2][BN * 64];

  // T1: bijective XCD swizzle
  int nwg = gridDim.x, orig = blockIdx.x;
  int q = nwg >> 3, r8 = nwg & 7;
  int xcd = orig & 7, loc = orig >> 3;
  int wg = (xcd < r8 ? xcd * (q + 1) : r8 * (q + 1) + (xcd - r8) * q) + loc;
  int tileM = wg / NTN, tileN = wg - tileM * NTN;   // tileN fastest: M-tile shared per XCD chunk
  if (tileM >= tile_off[8]) return;
  int e = 0;
  while (e < 7 && tile_off[e + 1] <= tileM) e++;
  int m0 = tileM * 256, n0 = tileN * BN;
  int t = threadIdx.x;
  int lane = t & 63, wv = t >> 6, quad = lane >> 4, lc = lane & 15;
  int wm = wv >> 2, wn = wv & 3;         // 2M x 4N wave grid

  // staging sources: chunk c covers LDS bytes [c*16, c*16+16): row = c>>3,
  // in-row 16B slot = c&7. Source is pre-XOR-swizzled so the *linear*
  // global_load_lds write produces the swizzled layout the reads expect
  // (rule 21: both-sides-or-neither).
  const ushort* aSrc[4];
#pragma unroll
  for (int i = 0; i < 4; i++){
    int c = i * 512 + t, rr = c >> 3;
    int o = ((c & 7) * 16) ^ ((rr & 7) << 4);
    size_t rowbase = (MODE == 0) ? (size_t)slot_row[m0 + rr] * KDIM
                                 : (size_t)(m0 + rr) * KDIM;
    aSrc[i] = Ag + rowbase + (o >> 1);
  }
  const ushort* bSrc[BQ];
#pragma unroll
  for (int i = 0; i < BQ; i++){
    int c = i * 512 + t, rr = c >> 3;
    int o = ((c & 7) * 16) ^ ((rr & 7) << 4);
    bSrc[i] = Wt + ((size_t)e * NTOTAL + n0 + rr) * (size_t)KDIM + (o >> 1);
  }

  // fragment-read offsets (ushort units); swizzle XOR on read side
  int foff = ((quad * 16) ^ ((lc & 7) << 4)) >> 1;
  int aRowBase = (wm * 128 + lc) * 64;
  int bRowBase = (wn * (NREP * 16) + lc) * 64;

  f32x4 acc[8][NREP] = {};
  bf16x8 a0[4], a1[4], b0[NREP], b1[NREP];

  // prologue: stage K-tile 0 into buffer 0
#pragma unroll
  for (int i = 0; i < 4; i++) GLDS(aSrc[i], &As[0][(i * 512 + t) * 8]);
#pragma unroll
  for (int i = 0; i < BQ; i++) GLDS(bSrc[i], &Bs[0][(i * 512 + t) * 8]);

  for (int kt = 0; kt < NT; ++kt){
    const int cur = kt & 1, nxt = cur ^ 1;
    const ushort* Ab = &As[cur][0];
    const ushort* Bb = &Bs[cur][0];
    ushort* Ad = &As[nxt][0];
    ushort* Bd = &Bs[nxt][0];
    const int ko = (kt + 1) * 64;
    const bool pf = (kt + 1 < NT);

    // head: issue first prefetch chunk, then counted wait for buf[cur].
    // Never drains the in-flight prefetch (T4).
    if (pf){
      GLDS(aSrc[0] + ko, Ad + (0 * 512 + t) * 8);
      GLDS(bSrc[0] + ko, Bd + (0 * 512 + t) * 8);
      SBAR;
      VMCNT(2);
    } else {
      SBAR;
      VMCNT(0);
    }
    SBAR; WBAR; SBAR;

    // phase 0: read frags(kk0, lower M half) + B(kk0), MFMA; prefetch chunk 1
    READ_Bf(b0, 0);
    READ_A(a0, 0, 0);
    MFMA_CL(a0, b0, 0);
    if (pf){
      GLDS(aSrc[1] + ko, Ad + (1 * 512 + t) * 8);
      if constexpr (BQ > 1) GLDS(bSrc[1] + ko, Bd + (1 * 512 + t) * 8);
    }
    READ_A(a1, 1, 0);
    SBAR; WBAR; SBAR;

    // phase 1: MFMA(kk0, upper M half); prefetch chunk 2; read kk1 frags
    MFMA_CL(a1, b0, 1);
    if (pf){
      GLDS(aSrc[2] + ko, Ad + (2 * 512 + t) * 8);
      if constexpr (BQ > 2) GLDS(bSrc[2] + ko, Bd + (2 * 512 + t) * 8);
    }
    READ_Bf(b1, 1);
    READ_A(a0, 0, 1);
    SBAR; WBAR; SBAR;

    // phase 2
    MFMA_CL(a0, b1, 0);
    if (pf){
      GLDS(aSrc[3] + ko, Ad + (3 * 512 + t) * 8);
      if constexpr (BQ > 3) GLDS(bSrc[3] + ko, Bd + (3 * 512 + t) * 8);
    }
    READ_A(a1, 1, 1);
    SBAR; WBAR; SBAR;

    // phase 3 + end barrier (protects buf[cur] against next iter's staging)
    MFMA_CL(a1, b1, 1);
    SBAR; WBAR; SBAR;
  }

  const float* be = bias + (size_t)e * NTOTAL;
  if constexpr (MODE == 0){
#pragma unroll
    for (int mi = 0; mi < 8; mi++)
#pragma unroll
      for (int rr = 0; rr < 4; rr++){
        int slot = m0 + wm * 128 + mi * 16 + quad * 4 + rr;
        ushort* hrow = Hout + (size_t)slot * NTOTAL;
#pragma unroll
        for (int nj = 0; nj < NREP; nj++){
          int col = n0 + wn * (NREP * 16) + nj * 16 + lc;
          float v = acc[mi][nj][rr] + be[col];
          hrow[col] = f2bf(fmaxf(v, 0.f));
        }
      }
  } else {
#pragma unroll
    for (int mi = 0; mi < 8; mi++)
#pragma unroll
      for (int rr = 0; rr < 4; rr++){
        int slot = m0 + wm * 128 + mi * 16 + quad * 4 + rr;
        float w = slot_w[slot];
        if (w == 0.f) continue;
        float* orow = out + (size_t)slot_row[slot] * NTOTAL;
#pragma unroll
        for (int nj = 0; nj < NREP; nj++){
          int col = n0 + wn * (NREP * 16) + nj * 16 + lc;
          atomicAdd(orow + col, w * (acc[mi][nj][rr] + be[col]));
        }
      }
  }
}

extern "C" void kernel_launch(void* const* d_in, const int* in_sizes, int n_in,
                              void* d_out, int out_size, void* d_ws, size_t ws_size,
                              hipStream_t stream){
  const float* x      = (const float*)d_in[0];
  const float* gate_w = (const float*)d_in[1];
  const float* gate_b = (const float*)d_in[2];
  const float* w1     = (const float*)d_in[3];
  const float* b1     = (const float*)d_in[4];
  const float* w2     = (const float*)d_in[5];
  const float* b2     = (const float*)d_in[6];
  float* out = (float*)d_out;

  char* ws = (char*)d_ws;
  ushort* WT    = (ushort*)(ws + OFF_WT);
  ushort* XB    = (ushort*)(ws + OFF_XB);
  ushort* H     = (ushort*)(ws + OFF_H);
  int*    SROW  = (int*)   (ws + OFF_SROW);
  float*  SW    = (float*) (ws + OFF_SW);
  int*    TIDX  = (int*)   (ws + OFF_TIDX);
  float*  TW    = (float*) (ws + OFF_TW);
  int*    COUNT = (int*)   (ws + OFF_CTRL);
  int*    FILL  = (int*)   (ws + OFF_CTRL + 32);
  int*    TOFF  = (int*)   (ws + OFF_CTRL + 64);
  float*  PART  = (float*) (ws + OFF_PART);

  float* aux_out   = out + (size_t)NTOK * DOUT;
  float* probs_out = aux_out + 1;

  hipMemsetAsync(d_out, 0, (size_t)out_size * 4, stream);
  hipMemsetAsync(ws + OFF_CTRL, 0, 128, stream);
  hipMemsetAsync(ws + OFF_SROW, 0, (size_t)SLOTCAP * 8, stream);  // slot_row + slot_w

  k_cvt_x<<<dim3((NTOK * DIN / 4) / 256), 256, 0, stream>>>((const float4*)x, (ushort4*)XB);
  k_transpose<<<dim3(DIN / 64, DH / 64, NE), 256, 0, stream>>>(w1, WT, DIN, DH);
  k_gate<<<dim3(NTOK / 4), 256, 0, stream>>>(x, gate_w, gate_b, probs_out, TIDX, TW, COUNT, PART);
  k_aux<<<dim3(1), 256, 0, stream>>>(PART, COUNT, aux_out, TOFF);
  k_scatter<<<dim3(NTOK * 2 / 256), 256, 0, stream>>>(TIDX, TW, TOFF, FILL, SROW, SW);

  // GEMM1: 256x256 tiles, H = relu(Xg @ W1^T + b1)
  k_gemm8<DIN, DH, 4, 0><<<dim3(MAXT * (DH / 256)), 512, 0, stream>>>(
      XB, WT, b1, SROW, SW, TOFF, H, nullptr);

  // W2^T into the same buffer (stream-ordered after gemm1)
  k_transpose<<<dim3(DH / 64, DOUT / 64, NE), 256, 0, stream>>>(w2, WT, DH, DOUT);

  // GEMM2: 256x128 tiles, out += w * (H @ W2^T + b2)
  k_gemm8<DH, DOUT, 2, 1><<<dim3(MAXT * (DOUT / 128)), 512, 0, stream>>>(
      H, WT, b2, SROW, SW, TOFF, nullptr, out);
}

// Round 6
// 969.929 us; speedup vs baseline: 1.3950x; 1.3950x over previous
//
#include <hip/hip_runtime.h>

#define NTOK 8192
#define DIN  1024
#define DH   4096
#define DOUT 1024
#define NE   8
#define MAXT 72                   // ceil(16384/256) + 8 experts of padding
#define SLOTCAP (MAXT*256)        // 18432

typedef __bf16 bf16x8 __attribute__((ext_vector_type(8)));
typedef float  f32x4  __attribute__((ext_vector_type(4)));
typedef int    i32x4  __attribute__((ext_vector_type(4)));

// ---- workspace layout (bytes) ----
constexpr size_t OFF_WT   = 0;            // 8*1024*4096*2 = 67108864
constexpr size_t OFF_XB   = 67108864;     // 8192*1024*2   = 16777216
constexpr size_t OFF_H    = 83886080;     // 18432*4096*2  = 150994944
constexpr size_t OFF_SROW = 234881024;    // 18432*4
constexpr size_t OFF_SW   = 234954752;    // 18432*4
constexpr size_t OFF_TIDX = 235028480;    // 8192*2*4
constexpr size_t OFF_TW   = 235094016;    // 8192*2*4
constexpr size_t OFF_CTRL = 235159552;    // count[8]@0, fill[8]@32, tile_off[9]@64
constexpr size_t OFF_PART = 235159680;    // 2048*8*4

__device__ __forceinline__ ushort f2bf(float f){
  unsigned u = __float_as_uint(f);
  u += 0x7fff + ((u >> 16) & 1);          // RNE
  return (ushort)(u >> 16);
}

#define GLDS(g,l) __builtin_amdgcn_global_load_lds( \
    (const __attribute__((address_space(1))) void*)(g), \
    (__attribute__((address_space(3))) void*)(l), 16, 0, 0)

#define SBAR __builtin_amdgcn_sched_barrier(0)
#define WBAR __builtin_amdgcn_s_barrier()
#define VMCNT0 asm volatile("s_waitcnt vmcnt(0)" ::: "memory")
#define LGKM0  do { asm volatile("s_waitcnt lgkmcnt(0)" ::: "memory"); SBAR; } while(0)

typedef __attribute__((address_space(3))) const ushort* lds_cp;
// inline-asm ds_read: invisible to the compiler's waitcnt pass (rule 18) --
// no auto vmcnt(0) drain before LDS reads. Consumed only after LGKM0+SBAR.
#define DSR(dst_bf, p) do { \
  i32x4 _t; \
  asm volatile("ds_read_b128 %0, %1" : "=v"(_t) : "v"((lds_cp)(p))); \
  dst_bf = __builtin_bit_cast(bf16x8, _t); \
} while(0)

// ---------------- x -> bf16 ----------------
__global__ void k_cvt_x(const float4* __restrict__ x, ushort4* __restrict__ xb){
  int i = blockIdx.x * 256 + threadIdx.x;
  float4 v = x[i];
  ushort4 o;
  o.x = f2bf(v.x); o.y = f2bf(v.y); o.z = f2bf(v.z); o.w = f2bf(v.w);
  xb[i] = o;
}

// ------------- W[E][R][C] f32 -> WT[E][C][R] bf16 -------------
__global__ void k_transpose(const float* __restrict__ W, ushort* __restrict__ WT, int R, int C){
  __shared__ ushort tl[64][65];
  int e  = blockIdx.z;
  int r0 = blockIdx.x * 64, c0 = blockIdx.y * 64;
  const float* Wp  = W  + (size_t)e * R * C;
  ushort*      WTp = WT + (size_t)e * R * C;
  int tr = threadIdx.x >> 6, tc = threadIdx.x & 63;
#pragma unroll
  for (int i = 0; i < 16; i++){
    int r = tr + i * 4;
    tl[r][tc] = f2bf(Wp[(size_t)(r0 + r) * C + c0 + tc]);
  }
  __syncthreads();
#pragma unroll
  for (int i = 0; i < 16; i++){
    int r = tr + i * 4;
    WTp[(size_t)(c0 + r) * R + r0 + tc] = tl[tc][r];
  }
}

// ---------------- gate: logits, softmax, top-2, counts ----------------
__global__ void k_gate(const float* __restrict__ x, const float* __restrict__ gw,
                       const float* __restrict__ gb, float* __restrict__ probs_out,
                       int* __restrict__ topk_idx, float* __restrict__ topk_w,
                       int* __restrict__ count, float* __restrict__ partial){
  __shared__ float psum[8];
  __shared__ int   pcnt[8];
  int wv = threadIdx.x >> 6, lane = threadIdx.x & 63;
  int row = blockIdx.x * 4 + wv;
  if (threadIdx.x < 8){ psum[threadIdx.x] = 0.f; pcnt[threadIdx.x] = 0; }
  __syncthreads();

  const float4* x4 = (const float4*)(x + (size_t)row * DIN);
  float acc[8];
#pragma unroll
  for (int e = 0; e < 8; e++) acc[e] = 0.f;
#pragma unroll
  for (int j = 0; j < 4; j++){
    float4 v = x4[j * 64 + lane];
    int kbase = (j * 64 + lane) * 4;
#pragma unroll
    for (int c = 0; c < 4; c++){
      float xv = (&v.x)[c];
      const float4* g4 = (const float4*)(gw + (size_t)(kbase + c) * 8);
      float4 g0 = g4[0], g1 = g4[1];
      acc[0] += xv * g0.x; acc[1] += xv * g0.y; acc[2] += xv * g0.z; acc[3] += xv * g0.w;
      acc[4] += xv * g1.x; acc[5] += xv * g1.y; acc[6] += xv * g1.z; acc[7] += xv * g1.w;
    }
  }
#pragma unroll
  for (int e = 0; e < 8; e++)
#pragma unroll
    for (int off = 32; off; off >>= 1) acc[e] += __shfl_xor(acc[e], off, 64);

  float lg[8], p[8], mx = -1e30f, s = 0.f;
#pragma unroll
  for (int e = 0; e < 8; e++){ lg[e] = acc[e] + gb[e]; mx = fmaxf(mx, lg[e]); }
#pragma unroll
  for (int e = 0; e < 8; e++){ p[e] = expf(lg[e] - mx); s += p[e]; }
  float inv = 1.f / s;
#pragma unroll
  for (int e = 0; e < 8; e++) p[e] *= inv;

  if (lane < 8) probs_out[(size_t)row * 8 + lane] = p[lane];

  if (lane == 0){
    int i1 = 0; float v1 = p[0];
#pragma unroll
    for (int e = 1; e < 8; e++) if (p[e] > v1){ v1 = p[e]; i1 = e; }
    int i2 = -1; float v2 = -1.f;
#pragma unroll
    for (int e = 0; e < 8; e++){ if (e == i1) continue; if (p[e] > v2){ v2 = p[e]; i2 = e; } }
    float denom = 1.f / (v1 + v2 + 1e-10f);
    topk_idx[row * 2]     = i1;  topk_idx[row * 2 + 1] = i2;
    topk_w  [row * 2]     = v1 * denom;  topk_w[row * 2 + 1] = v2 * denom;
    atomicAdd(&pcnt[i1], 1); atomicAdd(&pcnt[i2], 1);
  }
  if (lane < 8) atomicAdd(&psum[lane], p[lane]);
  __syncthreads();
  if (threadIdx.x < 8){
    partial[(size_t)blockIdx.x * 8 + threadIdx.x] = psum[threadIdx.x];
    if (pcnt[threadIdx.x]) atomicAdd(&count[threadIdx.x], pcnt[threadIdx.x]);
  }
}

// ---------------- aux loss + tile offsets (256-granular tiles) ----------------
__global__ void k_aux(const float* __restrict__ partial, const int* __restrict__ count,
                      float* __restrict__ aux_out, int* __restrict__ tile_off){
  __shared__ float red[256];
  __shared__ float tot[8];
  int t = threadIdx.x, e = t & 7;
  float s = 0.f;
  for (int b = (t >> 3); b < 2048; b += 32) s += partial[(size_t)b * 8 + e];
  red[t] = s; __syncthreads();
  if (t < 8){ float v = 0.f; for (int c = 0; c < 32; c++) v += red[c * 8 + t]; tot[t] = v; }
  __syncthreads();
  if (t == 0){
    float aux = 0.f;
    for (int i = 0; i < 8; i++){
      float m = tot[i] * (1.f / 8192.f);
      aux += m * logf(m * 8.f + 1e-10f);
    }
    aux_out[0] = aux;
    int off = 0;
    for (int i = 0; i < 8; i++){ tile_off[i] = off; off += (count[i] + 255) >> 8; }
    tile_off[8] = off;
  }
}

// ---------------- scatter assignments into padded slots ----------------
__global__ void k_scatter(const int* __restrict__ topk_idx, const float* __restrict__ topk_w,
                          const int* __restrict__ tile_off, int* __restrict__ fill,
                          int* __restrict__ slot_row, float* __restrict__ slot_w){
  int i = blockIdx.x * 256 + threadIdx.x;
  int row = i >> 1;
  int e = topk_idx[i];
  float w = topk_w[i];
  int lane = threadIdx.x & 63;
  int pos = 0;
#pragma unroll
  for (int ex = 0; ex < 8; ex++){
    unsigned long long mask = __ballot(e == ex);
    if (e == ex){
      int leader = __ffsll((long long)mask) - 1;
      int base = 0;
      if (lane == leader) base = atomicAdd(&fill[ex], (int)__popcll(mask));
      base = __shfl(base, leader, 64);
      pos = base + (int)__popcll(mask & ((1ull << lane) - 1ull));
    }
  }
  int slot = tile_off[e] * 256 + pos;
  slot_row[slot] = row;
  slot_w[slot]   = w;
}

// =====================================================================
// 256x(BN) 8-wave, BK=64, double-buffered, quadrant-phase GEMM.
// Phases per K-tile: 4 (gemm1, BN=256) / 2 (gemm2, BN=128), each phase:
//   [GLDS prefetch chunk (phases 0-1)] [asm ds_read_b128 x12] [s_barrier]
//   [lgkmcnt(0)+sched_barrier] [setprio1; 16 MFMA; setprio0]
// One vmcnt(0) per K-tile at the boundary (loads issued 2-4 phases prior).
// LDS reads are inline asm => compiler inserts NO vmcnt drains (rule 18).
// T1 XCD swizzle, T2 swizzle via pre-swizzled source (rule 21), T5 setprio.
// MODE 0: A = gathered XB rows, epilogue relu+bias -> H (bf16).
// MODE 1: A = H rows (slot-linear), epilogue weighted atomicAdd -> out.
// =====================================================================
template<int KDIM, int NTOTAL, int NREP, int MODE>
__global__ __launch_bounds__(512, 2) void k_gemm8(
    const ushort* __restrict__ Ag, const ushort* __restrict__ Wt,
    const float* __restrict__ bias, const int* __restrict__ slot_row,
    const float* __restrict__ slot_w, const int* __restrict__ tile_off,
    ushort* __restrict__ Hout, float* __restrict__ out)
{
  constexpr int BN  = NREP * 64;         // 256 (gemm1) / 128 (gemm2)
  constexpr int NTN = NTOTAL / BN;
  constexpr int NT  = KDIM / 64;         // K-tiles
  constexpr int BQ  = NREP;              // B staging chunks / thread
  constexpr int NQH = NREP / 2;          // N-halves per quadrant split: 2 / 1
  constexpr int P   = 2 * NQH;           // phases per K-tile: 4 / 2

  __shared__ __align__(16) ushort As[2][256 * 64];
  __shared__ __align__(16) ushort Bs[2][BN * 64];

  // T1: bijective XCD swizzle (grid %8==0 here)
  int nwg = gridDim.x, orig = blockIdx.x;
  int q8 = nwg >> 3, r8 = nwg & 7;
  int xcd = orig & 7, loc = orig >> 3;
  int wg = (xcd < r8 ? xcd * (q8 + 1) : r8 * (q8 + 1) + (xcd - r8) * q8) + loc;
  int tileM = wg / NTN, tileN = wg - tileM * NTN;
  if (tileM >= tile_off[8]) return;
  int e = 0;
  while (e < 7 && tile_off[e + 1] <= tileM) e++;
  int m0 = tileM * 256, n0 = tileN * BN;
  int t = threadIdx.x;
  int lane = t & 63, wv = t >> 6, quad = lane >> 4, lc = lane & 15;
  int wm = wv >> 2, wn = wv & 3;         // 2M x 4N wave grid

  // staging sources, pre-XOR-swizzled (rule 21): chunk c -> LDS bytes
  // [c*16, c*16+16), row = c>>3, slot = c&7; source byte offset
  // (slot*16) ^ ((row&7)<<4) so the linear GLDS write lands swizzled.
  const ushort* aSrc[4];
#pragma unroll
  for (int i = 0; i < 4; i++){
    int c = i * 512 + t, rr = c >> 3;
    int o = ((c & 7) * 16) ^ ((rr & 7) << 4);
    size_t rowbase = (MODE == 0) ? (size_t)slot_row[m0 + rr] * KDIM
                                 : (size_t)(m0 + rr) * KDIM;
    aSrc[i] = Ag + rowbase + (o >> 1);
  }
  const ushort* bSrc[BQ];
#pragma unroll
  for (int i = 0; i < BQ; i++){
    int c = i * 512 + t, rr = c >> 3;
    int o = ((c & 7) * 16) ^ ((rr & 7) << 4);
    bSrc[i] = Wt + ((size_t)e * NTOTAL + n0 + rr) * (size_t)KDIM + (o >> 1);
  }

  // fragment-read swizzle offset (ushort units); row&7 == lc&7 per lane
  int foff = ((quad * 16) ^ ((lc & 7) << 4)) >> 1;

  f32x4 acc[8][NREP] = {};

  // prologue: stage K-tile 0 into buffer 0, full drain + barrier
#pragma unroll
  for (int i = 0; i < 4; i++)  GLDS(aSrc[i], &As[0][(i * 512 + t) * 8]);
#pragma unroll
  for (int i = 0; i < BQ; i++) GLDS(bSrc[i], &Bs[0][(i * 512 + t) * 8]);
  SBAR; VMCNT0; WBAR; SBAR;

  for (int kt = 0; kt < NT; ++kt){
    const int cur = kt & 1, nxt = cur ^ 1;
    const ushort* Ab = &As[cur][0];
    const ushort* Bb = &Bs[cur][0];
    const int ko = (kt + 1) * 64;
    const bool pf = (kt + 1 < NT);

#pragma unroll
    for (int q = 0; q < P; q++){
      const int mh = q / NQH, nh = q % NQH;

      // prefetch next tile: all chunks issued across phases 0-1
      if (q == 0 && pf){
        GLDS(aSrc[0] + ko, &As[nxt][(0 * 512 + t) * 8]);
        GLDS(aSrc[1] + ko, &As[nxt][(1 * 512 + t) * 8]);
        GLDS(bSrc[0] + ko, &Bs[nxt][(0 * 512 + t) * 8]);
        if constexpr (BQ > 2) GLDS(bSrc[1] + ko, &Bs[nxt][(1 * 512 + t) * 8]);
      }
      if (q == 1 && pf){
        GLDS(aSrc[2] + ko, &As[nxt][(2 * 512 + t) * 8]);
        GLDS(aSrc[3] + ko, &As[nxt][(3 * 512 + t) * 8]);
        if constexpr (BQ > 2){
          GLDS(bSrc[2] + ko, &Bs[nxt][(2 * 512 + t) * 8]);
          GLDS(bSrc[3] + ko, &Bs[nxt][(3 * 512 + t) * 8]);
        } else {
          GLDS(bSrc[1] + ko, &Bs[nxt][(1 * 512 + t) * 8]);
        }
      }
      SBAR;

      // issue this quadrant's fragment reads (latency hides under barrier)
      bf16x8 af[4][2], bf[2][2];
#pragma unroll
      for (int i = 0; i < 4; i++)
#pragma unroll
        for (int kk = 0; kk < 2; kk++)
          DSR(af[i][kk], Ab + (wm * 128 + mh * 64 + i * 16 + lc) * 64 + (foff ^ (kk * 32)));
#pragma unroll
      for (int j = 0; j < 2; j++)
#pragma unroll
        for (int kk = 0; kk < 2; kk++)
          DSR(bf[j][kk], Bb + (wn * (NREP * 16) + (nh * 2 + j) * 16 + lc) * 64 + (foff ^ (kk * 32)));
      SBAR;
      WBAR;
      LGKM0;                       // + sched_barrier (rule 18)

      __builtin_amdgcn_s_setprio(1);
#pragma unroll
      for (int kk = 0; kk < 2; kk++)
#pragma unroll
        for (int i = 0; i < 4; i++)
#pragma unroll
          for (int j = 0; j < 2; j++)
            acc[mh * 4 + i][nh * 2 + j] = __builtin_amdgcn_mfma_f32_16x16x32_bf16(
                af[i][kk], bf[j][kk], acc[mh * 4 + i][nh * 2 + j], 0, 0, 0);
      __builtin_amdgcn_s_setprio(0);
      SBAR;
    }

    // tile boundary: next tile's loads (issued >=2 phases ago) must land;
    // the only outstanding vmem IS next tile's data -> vmcnt(0) loses nothing.
    if (pf) VMCNT0;
    WBAR; SBAR;
  }

  const float* be = bias + (size_t)e * NTOTAL;
  if constexpr (MODE == 0){
#pragma unroll
    for (int mi = 0; mi < 8; mi++)
#pragma unroll
      for (int rr = 0; rr < 4; rr++){
        int slot = m0 + wm * 128 + mi * 16 + quad * 4 + rr;
        ushort* hrow = Hout + (size_t)slot * NTOTAL;
#pragma unroll
        for (int nj = 0; nj < NREP; nj++){
          int col = n0 + wn * (NREP * 16) + nj * 16 + lc;
          float v = acc[mi][nj][rr] + be[col];
          hrow[col] = f2bf(fmaxf(v, 0.f));
        }
      }
  } else {
#pragma unroll
    for (int mi = 0; mi < 8; mi++)
#pragma unroll
      for (int rr = 0; rr < 4; rr++){
        int slot = m0 + wm * 128 + mi * 16 + quad * 4 + rr;
        float w = slot_w[slot];
        if (w == 0.f) continue;
        float* orow = out + (size_t)slot_row[slot] * NTOTAL;
#pragma unroll
        for (int nj = 0; nj < NREP; nj++){
          int col = n0 + wn * (NREP * 16) + nj * 16 + lc;
          atomicAdd(orow + col, w * (acc[mi][nj][rr] + be[col]));
        }
      }
  }
}

extern "C" void kernel_launch(void* const* d_in, const int* in_sizes, int n_in,
                              void* d_out, int out_size, void* d_ws, size_t ws_size,
                              hipStream_t stream){
  const float* x      = (const float*)d_in[0];
  const float* gate_w = (const float*)d_in[1];
  const float* gate_b = (const float*)d_in[2];
  const float* w1     = (const float*)d_in[3];
  const float* b1     = (const float*)d_in[4];
  const float* w2     = (const float*)d_in[5];
  const float* b2     = (const float*)d_in[6];
  float* out = (float*)d_out;

  char* ws = (char*)d_ws;
  ushort* WT    = (ushort*)(ws + OFF_WT);
  ushort* XB    = (ushort*)(ws + OFF_XB);
  ushort* H     = (ushort*)(ws + OFF_H);
  int*    SROW  = (int*)   (ws + OFF_SROW);
  float*  SW    = (float*) (ws + OFF_SW);
  int*    TIDX  = (int*)   (ws + OFF_TIDX);
  float*  TW    = (float*) (ws + OFF_TW);
  int*    COUNT = (int*)   (ws + OFF_CTRL);
  int*    FILL  = (int*)   (ws + OFF_CTRL + 32);
  int*    TOFF  = (int*)   (ws + OFF_CTRL + 64);
  float*  PART  = (float*) (ws + OFF_PART);

  float* aux_out   = out + (size_t)NTOK * DOUT;
  float* probs_out = aux_out + 1;

  hipMemsetAsync(d_out, 0, (size_t)out_size * 4, stream);
  hipMemsetAsync(ws + OFF_CTRL, 0, 128, stream);
  hipMemsetAsync(ws + OFF_SROW, 0, (size_t)SLOTCAP * 8, stream);  // slot_row + slot_w

  k_cvt_x<<<dim3((NTOK * DIN / 4) / 256), 256, 0, stream>>>((const float4*)x, (ushort4*)XB);
  k_transpose<<<dim3(DIN / 64, DH / 64, NE), 256, 0, stream>>>(w1, WT, DIN, DH);
  k_gate<<<dim3(NTOK / 4), 256, 0, stream>>>(x, gate_w, gate_b, probs_out, TIDX, TW, COUNT, PART);
  k_aux<<<dim3(1), 256, 0, stream>>>(PART, COUNT, aux_out, TOFF);
  k_scatter<<<dim3(NTOK * 2 / 256), 256, 0, stream>>>(TIDX, TW, TOFF, FILL, SROW, SW);

  // GEMM1: 256x256 tiles, H = relu(Xg @ W1^T + b1)
  k_gemm8<DIN, DH, 4, 0><<<dim3(MAXT * (DH / 256)), 512, 0, stream>>>(
      XB, WT, b1, SROW, SW, TOFF, H, nullptr);

  // W2^T into the same buffer (stream-ordered after gemm1)
  k_transpose<<<dim3(DH / 64, DOUT / 64, NE), 256, 0, stream>>>(w2, WT, DH, DOUT);

  // GEMM2: 256x128 tiles, out += w * (H @ W2^T + b2)
  k_gemm8<DH, DOUT, 2, 1><<<dim3(MAXT * (DOUT / 128)), 512, 0, stream>>>(
      H, WT, b2, SROW, SW, TOFF, nullptr, out);
}